// Round 9
// baseline (4106.993 us; speedup 1.0000x reference)
//
#include <hip/hip_runtime.h>
#include <cstdint>
#include <cstddef>

#define B_SZ 32
#define NPTS 16384
#define NSAMP 2048
#define F_IN 64
#define C_IN 67
#define D_OUT 128
#define FPS_THREADS 1024
#define PPT 16                     // points per thread
#define NPAIR (PPT / 2)            // 8 float2 pairs
#define NWAVE (FPS_THREADS / 64)   // 16

typedef float f32x2 __attribute__((ext_vector_type(2)));

// u64-key max across a wave level via DPP on both halves.
// bound_ctrl=false + old=self => invalid lanes keep own value (max-safe).
template <int CTRL>
__device__ __forceinline__ unsigned long long dpp_key_max(unsigned long long key) {
    const int lo = (int)(unsigned)key;
    const int hi = (int)(unsigned)(key >> 32);
    const int lo2 = __builtin_amdgcn_update_dpp(lo, lo, CTRL, 0xf, 0xf, false);
    const int hi2 = __builtin_amdgcn_update_dpp(hi, hi, CTRL, 0xf, 0xf, false);
    const unsigned long long ok =
        ((unsigned long long)(unsigned)hi2 << 32) | (unsigned)(unsigned)lo2;
    return ok > key ? ok : key;
}

__device__ __forceinline__ f32x2 pk_add(f32x2 a, f32x2 b) {
    f32x2 d;
    asm("v_pk_add_f32 %0, %1, %2" : "=v"(d) : "v"(a), "v"(b));
    return d;
}
__device__ __forceinline__ f32x2 pk_sq(f32x2 a) {
    f32x2 d;
    asm("v_pk_mul_f32 %0, %1, %1" : "=v"(d) : "v"(a));
    return d;
}

// ---------------------------------------------------------------------------
// FPS: one block per batch, 1024 threads, 16 pts/thread, 4 waves/SIMD.
// px,py,dist in VGPR f32x2 pairs (48 floats); pz pair-interleaved in LDS
// (ds_read_b64 on the LDS pipe -> zero VALU issue cost, and register state
// fits arch VGPRs, killing accvgpr-move traffic).
// Dist math: packed v_pk_add/mul via asm. Per-component rn; a+(-b)==a-b
// bit-exactly; association (dx^2+dy^2)+dz^2 matches reference -> identical
// argmax trajectory (absmax 0 with this exact formula since R1).
// Reduce per iteration (ONE barrier):
//   value-only running max -> local downward rescan (first match = lowest p)
//   -> u64 key (dist_bits<<32 | ~global_idx) -> 6-level DPP butterfly
//   -> lane63 writes LDS[parity][wave] -> barrier -> all threads redundantly
//   max 16 wave keys -> broadcast centroid load (L2-resident).
// ---------------------------------------------------------------------------
__global__ __launch_bounds__(FPS_THREADS, 4)
void fps_kernel(const float* __restrict__ xyz,       // [B, N, 3]
                const int* __restrict__ init_far,    // [B]
                int* __restrict__ idx_out,           // [B, S]
                float* __restrict__ newxyz_out)      // [B, S, 3]
{
    const int b = blockIdx.x;
    const int tid = threadIdx.x;
    const float* base = xyz + (size_t)b * NPTS * 3;

    __shared__ f32x2 s_zp[NPAIR][FPS_THREADS];       // 64 KB
    __shared__ unsigned long long s_key[2][NWAVE];

    f32x2 px2[NPAIR], py2[NPAIR], dist2[NPAIR];
#pragma unroll
    for (int k = 0; k < NPAIR; ++k) {
        const int i0 = tid + (2 * k) * FPS_THREADS;  // ascending in (k,half)
        const int i1 = i0 + FPS_THREADS;
        px2[k] = f32x2{base[i0 * 3 + 0], base[i1 * 3 + 0]};
        py2[k] = f32x2{base[i0 * 3 + 1], base[i1 * 3 + 1]};
        s_zp[k][tid] = f32x2{base[i0 * 3 + 2], base[i1 * 3 + 2]};
        dist2[k] = f32x2{1e10f, 1e10f};
    }

    int cur = init_far[b];
    float cx = base[cur * 3 + 0];
    float cy = base[cur * 3 + 1];
    float cz = base[cur * 3 + 2];
    __syncthreads();

    const int lane = tid & 63;
    const int wave = tid >> 6;

    for (int s = 0; s < NSAMP; ++s) {
        const int q = s & 1;
        // record BEFORE update (reference scan semantics); fire-and-forget
        if (tid == 0) {
            idx_out[b * NSAMP + s] = cur;
            float* o = newxyz_out + (size_t)(b * NSAMP + s) * 3;
            o[0] = cx; o[1] = cy; o[2] = cz;
        }

        // negated centroid pairs: a + (-c) is bit-identical to a - c
        const f32x2 ncx2 = {-cx, -cx};
        const f32x2 ncy2 = {-cy, -cy};
        const f32x2 ncz2 = {-cz, -cz};

        // A: packed distance update + value-only running max
        float best = 0.0f;
#pragma unroll
        for (int k = 0; k < NPAIR; ++k) {
            const f32x2 z01 = s_zp[k][tid];          // ds_read_b64 (LDS pipe)
            const f32x2 dx = pk_add(px2[k], ncx2);
            const f32x2 dy = pk_add(py2[k], ncy2);
            const f32x2 dz = pk_add(z01,   ncz2);
            const f32x2 t0 = pk_sq(dx);
            const f32x2 t1 = pk_sq(dy);
            const f32x2 t2 = pk_sq(dz);
            const f32x2 t3 = pk_add(t0, t1);
            const f32x2 d  = pk_add(t3, t2);
            const float nd0 = fminf(dist2[k].x, d.x);
            const float nd1 = fminf(dist2[k].y, d.y);
            dist2[k].x = nd0;
            dist2[k].y = nd1;
            best = fmaxf(fmaxf(best, nd0), nd1);     // -> v_max3
        }

        // B: local rescan, downward -> smallest p with dist[p]==best
        int bp = 0;
#pragma unroll
        for (int p = PPT - 1; p >= 0; --p) {
            const float dv = (p & 1) ? dist2[p >> 1].y : dist2[p >> 1].x;
            bp = (dv == best) ? p : bp;
        }
        const int bi = tid + bp * FPS_THREADS;

        // C: packed key (max dist; tie -> lowest global index)
        unsigned long long key =
            ((unsigned long long)__float_as_uint(best) << 32) |
            (unsigned long long)(~(unsigned)bi);

        // D: 6-level DPP butterfly; lane 63 complete
        key = dpp_key_max<0x111>(key);   // row_shr:1
        key = dpp_key_max<0x112>(key);   // row_shr:2
        key = dpp_key_max<0x114>(key);   // row_shr:4
        key = dpp_key_max<0x118>(key);   // row_shr:8
        key = dpp_key_max<0x142>(key);   // row_bcast:15
        key = dpp_key_max<0x143>(key);   // row_bcast:31
        if (lane == 63) s_key[q][wave] = key;
        __syncthreads();                 // the only barrier

        // E: redundant block reduce over 16 wave keys
        unsigned long long fin = s_key[q][0];
#pragma unroll
        for (int w = 1; w < NWAVE; ++w) {
            const unsigned long long k2 = s_key[q][w];
            fin = (k2 > fin) ? k2 : fin;
        }
        const int vi = (int)(~(unsigned)(fin & 0xFFFFFFFFull));
        cur = vi;
        // F: broadcast centroid load (uniform address, L2-resident)
        cx = base[vi * 3 + 0];
        cy = base[vi * 3 + 1];
        cz = base[vi * 3 + 2];
    }
}

// ---------------------------------------------------------------------------
// Kernel 2: gather selected rows, 1x1 conv (x @ W + b), ReLU.
// ---------------------------------------------------------------------------
#define SAMP_PER_BLK 16

__global__ __launch_bounds__(256)
void gather_linear_relu_kernel(const float* __restrict__ xyz,    // [B,N,3]
                               const float* __restrict__ feats,  // [B,N,F]
                               const int* __restrict__ idx,      // [B*S]
                               const float* __restrict__ W,      // [67,128]
                               const float* __restrict__ bias,   // [128]
                               float* __restrict__ out)          // [B*S,128]
{
    __shared__ float sW[C_IN][D_OUT];
    __shared__ float sX[SAMP_PER_BLK][C_IN + 1];
    __shared__ float sB[D_OUT];

    const int tid = threadIdx.x;

    for (int i = tid; i < C_IN * D_OUT; i += 256)
        (&sW[0][0])[i] = W[i];
    if (tid < D_OUT) sB[tid] = bias[tid];

    const int gs0 = blockIdx.x * SAMP_PER_BLK;

    {
        const int si = tid >> 4;
        const int j  = tid & 15;
        const int gs = gs0 + si;
        const int bb = gs >> 11;
        const int pt = idx[gs];
        const float* frow = feats + ((size_t)bb * NPTS + pt) * F_IN;
        const float* xrow = xyz   + ((size_t)bb * NPTS + pt) * 3;
        for (int c = j; c < F_IN; c += 16) sX[si][c] = frow[c];
        if (j < 3) sX[si][F_IN + j] = xrow[j];
    }
    __syncthreads();

    const int d = tid & 127;
    const int g = tid >> 7;
    float acc[8];
#pragma unroll
    for (int k = 0; k < 8; ++k) acc[k] = 0.0f;

    for (int c = 0; c < C_IN; ++c) {
        const float w = sW[c][d];
#pragma unroll
        for (int k = 0; k < 8; ++k)
            acc[k] = fmaf(sX[g * 8 + k][c], w, acc[k]);
    }

    const float bv = sB[d];
#pragma unroll
    for (int k = 0; k < 8; ++k) {
        const int gs = gs0 + g * 8 + k;
        const float v = acc[k] + bv;
        out[(size_t)gs * D_OUT + d] = fmaxf(v, 0.0f);
    }
}

// ---------------------------------------------------------------------------
extern "C" void kernel_launch(void* const* d_in, const int* in_sizes, int n_in,
                              void* d_out, int out_size, void* d_ws, size_t ws_size,
                              hipStream_t stream) {
    const float* xyz      = (const float*)d_in[0];
    const float* feats    = (const float*)d_in[1];
    const int*   init_far = (const int*)d_in[2];
    const float* W        = (const float*)d_in[3];
    const float* bias     = (const float*)d_in[4];

    float* out_newxyz = (float*)d_out;
    float* out_conv   = (float*)d_out + (size_t)B_SZ * NSAMP * 3;
    int*   idx_ws     = (int*)d_ws;

    fps_kernel<<<B_SZ, FPS_THREADS, 0, stream>>>(xyz, init_far, idx_ws, out_newxyz);

    const int nblocks = (B_SZ * NSAMP) / SAMP_PER_BLK;
    gather_linear_relu_kernel<<<nblocks, 256, 0, stream>>>(
        xyz, feats, idx_ws, W, bias, out_conv);
}

// Round 10
// 3726.793 us; speedup vs baseline: 1.1020x; 1.1020x over previous
//
#include <hip/hip_runtime.h>
#include <cstdint>
#include <cstddef>

#define B_SZ 32
#define NPTS 16384
#define NSAMP 2048
#define F_IN 64
#define C_IN 67
#define D_OUT 128
#define FPS_THREADS 1024
#define PPT 16                     // points per thread
#define NPAIR (PPT / 2)            // 8 float2 pairs
#define NWAVE (FPS_THREADS / 64)   // 16

typedef float f32x2 __attribute__((ext_vector_type(2)));

// u64-key max across a wave level via DPP on both halves.
// bound_ctrl=false + old=self => invalid lanes keep own value (max-safe).
template <int CTRL>
__device__ __forceinline__ unsigned long long dpp_key_max(unsigned long long key) {
    const int lo = (int)(unsigned)key;
    const int hi = (int)(unsigned)(key >> 32);
    const int lo2 = __builtin_amdgcn_update_dpp(lo, lo, CTRL, 0xf, 0xf, false);
    const int hi2 = __builtin_amdgcn_update_dpp(hi, hi, CTRL, 0xf, 0xf, false);
    const unsigned long long ok =
        ((unsigned long long)(unsigned)hi2 << 32) | (unsigned)(unsigned)lo2;
    return ok > key ? ok : key;
}

__device__ __forceinline__ f32x2 pk_add(f32x2 a, f32x2 b) {
    f32x2 d;
    asm("v_pk_add_f32 %0, %1, %2" : "=v"(d) : "v"(a), "v"(b));
    return d;
}
__device__ __forceinline__ f32x2 pk_sq(f32x2 a) {
    f32x2 d;
    asm("v_pk_mul_f32 %0, %1, %1" : "=v"(d) : "v"(a));
    return d;
}

// ---------------------------------------------------------------------------
// FPS: one block per batch, 1024 threads, 16 pts/thread, 4 waves/SIMD.
// ALL state (px,py,pz,dist as f32x2 pairs = 64 floats) in arch VGPRs:
// amdgpu_waves_per_eu(4,4) pins the allocator to the real occupancy (one
// 1024-thread block per CU) -> 128-VGPR budget -> no AGPR split, no
// v_accvgpr move tax (R8/R9 showed VGPR_Count 52/40 with 64+ floats of
// state = hidden moves in the hot loop).
// Dist math: packed v_pk_add/mul via asm. Per-component rn; a+(-b)==a-b
// bit-exactly; association (dx^2+dy^2)+dz^2 matches reference -> identical
// argmax trajectory (absmax 0 with this formula since R1). No LDS in the
// distance path (R9 proved ds_read stalls cost more than the VALU saved).
// Reduce per iteration (ONE barrier):
//   value-only running max -> local downward rescan (first match = lowest p)
//   -> u64 key (dist_bits<<32 | ~global_idx) -> 6-level DPP butterfly
//   -> lane63 writes LDS[parity][wave] -> barrier -> all threads redundantly
//   max 16 wave keys -> readfirstlane -> scalar centroid load (SMEM pipe).
// ---------------------------------------------------------------------------
__global__
__attribute__((amdgpu_flat_work_group_size(1024, 1024)))
__attribute__((amdgpu_waves_per_eu(4, 4)))
void fps_kernel(const float* __restrict__ xyz,       // [B, N, 3]
                const int* __restrict__ init_far,    // [B]
                int* __restrict__ idx_out,           // [B, S]
                float* __restrict__ newxyz_out)      // [B, S, 3]
{
    const int b = blockIdx.x;
    const int tid = threadIdx.x;
    const float* base = xyz + (size_t)b * NPTS * 3;

    __shared__ unsigned long long s_key[2][NWAVE];

    f32x2 px2[NPAIR], py2[NPAIR], pz2[NPAIR], dist2[NPAIR];
#pragma unroll
    for (int k = 0; k < NPAIR; ++k) {
        const int i0 = tid + (2 * k) * FPS_THREADS;  // ascending in (k,half)
        const int i1 = i0 + FPS_THREADS;
        px2[k] = f32x2{base[i0 * 3 + 0], base[i1 * 3 + 0]};
        py2[k] = f32x2{base[i0 * 3 + 1], base[i1 * 3 + 1]};
        pz2[k] = f32x2{base[i0 * 3 + 2], base[i1 * 3 + 2]};
        dist2[k] = f32x2{1e10f, 1e10f};
    }

    int cur = init_far[b];
    float cx = base[cur * 3 + 0];
    float cy = base[cur * 3 + 1];
    float cz = base[cur * 3 + 2];
    __syncthreads();

    const int lane = tid & 63;
    const int wave = tid >> 6;

    for (int s = 0; s < NSAMP; ++s) {
        const int q = s & 1;
        // record BEFORE update (reference scan semantics); fire-and-forget
        if (tid == 0) {
            idx_out[b * NSAMP + s] = cur;
            float* o = newxyz_out + (size_t)(b * NSAMP + s) * 3;
            o[0] = cx; o[1] = cy; o[2] = cz;
        }

        // negated centroid pairs: a + (-c) is bit-identical to a - c
        const f32x2 ncx2 = {-cx, -cx};
        const f32x2 ncy2 = {-cy, -cy};
        const f32x2 ncz2 = {-cz, -cz};

        // A: packed distance update + value-only running max
        float best = 0.0f;
#pragma unroll
        for (int k = 0; k < NPAIR; ++k) {
            const f32x2 dx = pk_add(px2[k], ncx2);
            const f32x2 dy = pk_add(py2[k], ncy2);
            const f32x2 dz = pk_add(pz2[k], ncz2);
            const f32x2 t0 = pk_sq(dx);
            const f32x2 t1 = pk_sq(dy);
            const f32x2 t2 = pk_sq(dz);
            const f32x2 t3 = pk_add(t0, t1);
            const f32x2 d  = pk_add(t3, t2);
            const float nd0 = fminf(dist2[k].x, d.x);
            const float nd1 = fminf(dist2[k].y, d.y);
            dist2[k].x = nd0;
            dist2[k].y = nd1;
            best = fmaxf(fmaxf(best, nd0), nd1);     // -> v_max3
        }

        // B: local rescan, downward -> smallest p with dist[p]==best
        int bp = 0;
#pragma unroll
        for (int p = PPT - 1; p >= 0; --p) {
            const float dv = (p & 1) ? dist2[p >> 1].y : dist2[p >> 1].x;
            bp = (dv == best) ? p : bp;
        }
        const int bi = tid + bp * FPS_THREADS;

        // C: packed key (max dist; tie -> lowest global index)
        unsigned long long key =
            ((unsigned long long)__float_as_uint(best) << 32) |
            (unsigned long long)(~(unsigned)bi);

        // D: 6-level DPP butterfly; lane 63 complete
        key = dpp_key_max<0x111>(key);   // row_shr:1
        key = dpp_key_max<0x112>(key);   // row_shr:2
        key = dpp_key_max<0x114>(key);   // row_shr:4
        key = dpp_key_max<0x118>(key);   // row_shr:8
        key = dpp_key_max<0x142>(key);   // row_bcast:15
        key = dpp_key_max<0x143>(key);   // row_bcast:31
        if (lane == 63) s_key[q][wave] = key;
        __syncthreads();                 // the only barrier

        // E: redundant block reduce over 16 wave keys
        unsigned long long fin = s_key[q][0];
#pragma unroll
        for (int w = 1; w < NWAVE; ++w) {
            const unsigned long long k2 = s_key[q][w];
            fin = (k2 > fin) ? k2 : fin;
        }
        const int vi = (int)(~(unsigned)(fin & 0xFFFFFFFFull));
        cur = vi;

        // F: scalar (SMEM) centroid load — uniform by construction
        const int vs = __builtin_amdgcn_readfirstlane(vi);
        cx = base[vs * 3 + 0];
        cy = base[vs * 3 + 1];
        cz = base[vs * 3 + 2];
    }
}

// ---------------------------------------------------------------------------
// Kernel 2: gather selected rows, 1x1 conv (x @ W + b), ReLU.
// ---------------------------------------------------------------------------
#define SAMP_PER_BLK 16

__global__ __launch_bounds__(256)
void gather_linear_relu_kernel(const float* __restrict__ xyz,    // [B,N,3]
                               const float* __restrict__ feats,  // [B,N,F]
                               const int* __restrict__ idx,      // [B*S]
                               const float* __restrict__ W,      // [67,128]
                               const float* __restrict__ bias,   // [128]
                               float* __restrict__ out)          // [B*S,128]
{
    __shared__ float sW[C_IN][D_OUT];
    __shared__ float sX[SAMP_PER_BLK][C_IN + 1];
    __shared__ float sB[D_OUT];

    const int tid = threadIdx.x;

    for (int i = tid; i < C_IN * D_OUT; i += 256)
        (&sW[0][0])[i] = W[i];
    if (tid < D_OUT) sB[tid] = bias[tid];

    const int gs0 = blockIdx.x * SAMP_PER_BLK;

    {
        const int si = tid >> 4;
        const int j  = tid & 15;
        const int gs = gs0 + si;
        const int bb = gs >> 11;
        const int pt = idx[gs];
        const float* frow = feats + ((size_t)bb * NPTS + pt) * F_IN;
        const float* xrow = xyz   + ((size_t)bb * NPTS + pt) * 3;
        for (int c = j; c < F_IN; c += 16) sX[si][c] = frow[c];
        if (j < 3) sX[si][F_IN + j] = xrow[j];
    }
    __syncthreads();

    const int d = tid & 127;
    const int g = tid >> 7;
    float acc[8];
#pragma unroll
    for (int k = 0; k < 8; ++k) acc[k] = 0.0f;

    for (int c = 0; c < C_IN; ++c) {
        const float w = sW[c][d];
#pragma unroll
        for (int k = 0; k < 8; ++k)
            acc[k] = fmaf(sX[g * 8 + k][c], w, acc[k]);
    }

    const float bv = sB[d];
#pragma unroll
    for (int k = 0; k < 8; ++k) {
        const int gs = gs0 + g * 8 + k;
        const float v = acc[k] + bv;
        out[(size_t)gs * D_OUT + d] = fmaxf(v, 0.0f);
    }
}

// ---------------------------------------------------------------------------
extern "C" void kernel_launch(void* const* d_in, const int* in_sizes, int n_in,
                              void* d_out, int out_size, void* d_ws, size_t ws_size,
                              hipStream_t stream) {
    const float* xyz      = (const float*)d_in[0];
    const float* feats    = (const float*)d_in[1];
    const int*   init_far = (const int*)d_in[2];
    const float* W        = (const float*)d_in[3];
    const float* bias     = (const float*)d_in[4];

    float* out_newxyz = (float*)d_out;
    float* out_conv   = (float*)d_out + (size_t)B_SZ * NSAMP * 3;
    int*   idx_ws     = (int*)d_ws;

    fps_kernel<<<B_SZ, FPS_THREADS, 0, stream>>>(xyz, init_far, idx_ws, out_newxyz);

    const int nblocks = (B_SZ * NSAMP) / SAMP_PER_BLK;
    gather_linear_relu_kernel<<<nblocks, 256, 0, stream>>>(
        xyz, feats, idx_ws, W, bias, out_conv);
}

// Round 11
// 2738.158 us; speedup vs baseline: 1.4999x; 1.3611x over previous
//
#include <hip/hip_runtime.h>
#include <cstdint>
#include <cstddef>

#define B_SZ 32
#define NPTS 16384
#define NSAMP 2048
#define F_IN 64
#define C_IN 67
#define D_OUT 128
#define FPS_THREADS 1024
#define PPT 16                     // points per thread
#define NWAVE 16
#define NCELL 512                  // 8x8x8 Morton cells

// ---- DPP wave reduce helpers (row_shr 1/2/4/8 + row_bcast 15/31 -> lane63) ----
template <int CTRL>
__device__ __forceinline__ float dpp_maxf(float v) {
    const int iv = __float_as_int(v);
    const int mv = __builtin_amdgcn_update_dpp(iv, iv, CTRL, 0xf, 0xf, false);
    return fmaxf(v, __int_as_float(mv));
}
template <int CTRL>
__device__ __forceinline__ float dpp_minf(float v) {
    const int iv = __float_as_int(v);
    const int mv = __builtin_amdgcn_update_dpp(iv, iv, CTRL, 0xf, 0xf, false);
    return fminf(v, __int_as_float(mv));
}
__device__ __forceinline__ float wave_max_all(float v) {
    v = dpp_maxf<0x111>(v); v = dpp_maxf<0x112>(v); v = dpp_maxf<0x114>(v);
    v = dpp_maxf<0x118>(v); v = dpp_maxf<0x142>(v); v = dpp_maxf<0x143>(v);
    return __shfl(v, 63, 64);
}
__device__ __forceinline__ float wave_min_all(float v) {
    v = dpp_minf<0x111>(v); v = dpp_minf<0x112>(v); v = dpp_minf<0x114>(v);
    v = dpp_minf<0x118>(v); v = dpp_minf<0x142>(v); v = dpp_minf<0x143>(v);
    return __shfl(v, 63, 64);
}
template <int CTRL>
__device__ __forceinline__ unsigned long long dpp_key_max(unsigned long long key) {
    const int lo = (int)(unsigned)key;
    const int hi = (int)(unsigned)(key >> 32);
    const int lo2 = __builtin_amdgcn_update_dpp(lo, lo, CTRL, 0xf, 0xf, false);
    const int hi2 = __builtin_amdgcn_update_dpp(hi, hi, CTRL, 0xf, 0xf, false);
    const unsigned long long ok =
        ((unsigned long long)(unsigned)hi2 << 32) | (unsigned long long)(unsigned)lo2;
    return ok > key ? ok : key;
}

// ---------------------------------------------------------------------------
// FPS with exact wave-level skipping.
// Init: 512-cell Morton binning (LDS hist + Hillis-Steele scan + scatter),
// waves own spatially-compact 1024-point sets; wave bbox from actual points.
// Per iteration (ONE barrier, parity key slots as in R8):
//   skip test: L = dist^2(bbox, centroid); if L*(1-1e-5) > wave_max, the wave
//   provably cannot change any dist (fp-safe: d_comp >= wave_max >= dist[p],
//   so fminf is a no-op) -> skip update + key recompute, reuse cached key.
//   Winner's wave always active (contains vi -> L == 0).
//   Active: exact rn dist update (same formula/order as reference), value max,
//   rescan with ORIGINAL-index tie-break (min orig among dist==best),
//   u64 key (dist_bits<<32 | ~orig_idx) == jnp.argmax semantics, DPP butterfly.
//   All waves: lane63 writes (cached) key -> barrier -> redundant 16-key max
//   -> scalar centroid load.
// ---------------------------------------------------------------------------
__global__ __launch_bounds__(FPS_THREADS, 4)
void fps_kernel(const float* __restrict__ xyz,       // [B, N, 3]
                const int* __restrict__ init_far,    // [B]
                int* __restrict__ idx_out,           // [B, S]
                float* __restrict__ newxyz_out)      // [B, S, 3]
{
    const int b = blockIdx.x;
    const int tid = threadIdx.x;
    const int lane = tid & 63;
    const int wave = tid >> 6;
    const float* base = xyz + (size_t)b * NPTS * 3;

    __shared__ unsigned short s_sidx[NPTS];          // 32 KB sorted orig idx
    __shared__ unsigned int s_hist[NCELL];
    __shared__ unsigned int s_start[NCELL];
    __shared__ unsigned long long s_key[2][NWAVE];

    // ---- phase 0/1: cell ids + histogram ----
    if (tid < NCELL) s_hist[tid] = 0u;
    __syncthreads();

    unsigned cells[PPT];
#pragma unroll
    for (int p = 0; p < PPT; ++p) {
        const int i = tid + p * FPS_THREADS;
        const float x = base[i * 3 + 0];
        const float y = base[i * 3 + 1];
        const float z = base[i * 3 + 2];
        const int qx = (int)fminf(fmaxf((x + 3.0f) * 1.3333333f, 0.0f), 7.0f);
        const int qy = (int)fminf(fmaxf((y + 3.0f) * 1.3333333f, 0.0f), 7.0f);
        const int qz = (int)fminf(fmaxf((z + 3.0f) * 1.3333333f, 0.0f), 7.0f);
        unsigned m = 0;
#pragma unroll
        for (int t = 0; t < 3; ++t)
            m |= (((unsigned)(qx >> t) & 1u) << (3 * t + 2)) |
                 (((unsigned)(qy >> t) & 1u) << (3 * t + 1)) |
                 (((unsigned)(qz >> t) & 1u) << (3 * t + 0));
        cells[p] = m;
        atomicAdd(&s_hist[m], 1u);
    }
    __syncthreads();

    // ---- phase 2: exclusive prefix sum (Hillis-Steele) ----
    for (int off = 1; off < NCELL; off <<= 1) {
        unsigned v = 0;
        if (tid < NCELL) {
            v = s_hist[tid];
            if (tid >= off) v += s_hist[tid - off];
        }
        __syncthreads();
        if (tid < NCELL) s_hist[tid] = v;
        __syncthreads();
    }
    if (tid < NCELL) s_start[tid] = (tid == 0) ? 0u : s_hist[tid - 1];
    __syncthreads();

    // ---- phase 3: scatter orig indices into cell-sorted order ----
#pragma unroll
    for (int p = 0; p < PPT; ++p) {
        const int i = tid + p * FPS_THREADS;
        const unsigned pos = atomicAdd(&s_start[cells[p]], 1u);
        s_sidx[pos] = (unsigned short)i;
    }
    __syncthreads();

    // ---- phase 4: regather wave-contiguous points + bbox ----
    float px[PPT], py[PPT], pz[PPT], dist[PPT];
    unsigned oidx[PPT / 2];                          // packed u16 orig indices
    float lmnx = 1e30f, lmny = 1e30f, lmnz = 1e30f;
    float lmxx = -1e30f, lmxy = -1e30f, lmxz = -1e30f;
#pragma unroll
    for (int p = 0; p < PPT; ++p) {
        const int spos = wave * 1024 + p * 64 + lane;
        const unsigned oi = (unsigned)s_sidx[spos];
        const float x = base[oi * 3 + 0];
        const float y = base[oi * 3 + 1];
        const float z = base[oi * 3 + 2];
        px[p] = x; py[p] = y; pz[p] = z; dist[p] = 1e10f;
        if (p & 1) oidx[p >> 1] |= oi << 16; else oidx[p >> 1] = oi;
        lmnx = fminf(lmnx, x); lmny = fminf(lmny, y); lmnz = fminf(lmnz, z);
        lmxx = fmaxf(lmxx, x); lmxy = fmaxf(lmxy, y); lmxz = fmaxf(lmxz, z);
    }
    const float bmnx = wave_min_all(lmnx), bmny = wave_min_all(lmny), bmnz = wave_min_all(lmnz);
    const float bmxx = wave_max_all(lmxx), bmxy = wave_max_all(lmxy), bmxz = wave_max_all(lmxz);

    float wmax_u = 1e10f;                // wave's current max dist (uniform)
    unsigned long long ckey = 0ull;      // cached wave key (lane63's is real)

    int cur = init_far[b];
    float cx = base[cur * 3 + 0];
    float cy = base[cur * 3 + 1];
    float cz = base[cur * 3 + 2];
    __syncthreads();

    for (int s = 0; s < NSAMP; ++s) {
        const int q = s & 1;
        // record BEFORE update (reference scan semantics)
        if (tid == 0) {
            idx_out[b * NSAMP + s] = cur;
            float* o = newxyz_out + (size_t)(b * NSAMP + s) * 3;
            o[0] = cx; o[1] = cy; o[2] = cz;
        }

        // wave-uniform skip test: conservative lower bound of ||p-c||^2
        const float dxl = fmaxf(fmaxf(bmnx - cx, cx - bmxx), 0.0f);
        const float dyl = fmaxf(fmaxf(bmny - cy, cy - bmxy), 0.0f);
        const float dzl = fmaxf(fmaxf(bmnz - cz, cz - bmxz), 0.0f);
        const float L = dxl * dxl + dyl * dyl + dzl * dzl;
        const float Lsafe = L * 0.99999f;            // 1e-5 slack >> fp error

        if (!(Lsafe > wmax_u)) {
            // active: exact dist update (same rn ops/order as reference)
            float best = 0.0f;
#pragma unroll
            for (int p = 0; p < PPT; ++p) {
                const float dx = __fsub_rn(px[p], cx);
                const float dy = __fsub_rn(py[p], cy);
                const float dz = __fsub_rn(pz[p], cz);
                const float d  = __fadd_rn(__fadd_rn(__fmul_rn(dx, dx),
                                                     __fmul_rn(dy, dy)),
                                           __fmul_rn(dz, dz));
                const float nd = fminf(dist[p], d);
                dist[p] = nd;
                best = fmaxf(best, nd);
            }
            // min ORIGINAL index among exact matches (jnp.argmax tie rule)
            unsigned bo = 0xFFFFFFFFu;
#pragma unroll
            for (int p = 0; p < PPT; ++p) {
                const unsigned oi = (oidx[p >> 1] >> ((p & 1) * 16)) & 0xFFFFu;
                bo = (dist[p] == best) ? min(bo, oi) : bo;
            }
            unsigned long long key =
                ((unsigned long long)__float_as_uint(best) << 32) |
                (unsigned long long)(~bo);
            key = dpp_key_max<0x111>(key);
            key = dpp_key_max<0x112>(key);
            key = dpp_key_max<0x114>(key);
            key = dpp_key_max<0x118>(key);
            key = dpp_key_max<0x142>(key);
            key = dpp_key_max<0x143>(key);
            ckey = key;                              // lane63 holds wave key
            wmax_u = __shfl(__uint_as_float((unsigned)(key >> 32)), 63, 64);
        }

        if (lane == 63) s_key[q][wave] = ckey;
        __syncthreads();                             // the only barrier

        unsigned long long fin = s_key[q][0];
#pragma unroll
        for (int w = 1; w < NWAVE; ++w) {
            const unsigned long long k2 = s_key[q][w];
            fin = (k2 > fin) ? k2 : fin;
        }
        const int vi = (int)(~(unsigned)(fin & 0xFFFFFFFFull));
        cur = vi;
        const int vs = __builtin_amdgcn_readfirstlane(vi);
        cx = base[vs * 3 + 0];
        cy = base[vs * 3 + 1];
        cz = base[vs * 3 + 2];
    }
}

// ---------------------------------------------------------------------------
// Kernel 2: gather selected rows, 1x1 conv (x @ W + b), ReLU.
// ---------------------------------------------------------------------------
#define SAMP_PER_BLK 16

__global__ __launch_bounds__(256)
void gather_linear_relu_kernel(const float* __restrict__ xyz,    // [B,N,3]
                               const float* __restrict__ feats,  // [B,N,F]
                               const int* __restrict__ idx,      // [B*S]
                               const float* __restrict__ W,      // [67,128]
                               const float* __restrict__ bias,   // [128]
                               float* __restrict__ out)          // [B*S,128]
{
    __shared__ float sW[C_IN][D_OUT];
    __shared__ float sX[SAMP_PER_BLK][C_IN + 1];
    __shared__ float sB[D_OUT];

    const int tid = threadIdx.x;

    for (int i = tid; i < C_IN * D_OUT; i += 256)
        (&sW[0][0])[i] = W[i];
    if (tid < D_OUT) sB[tid] = bias[tid];

    const int gs0 = blockIdx.x * SAMP_PER_BLK;

    {
        const int si = tid >> 4;
        const int j  = tid & 15;
        const int gs = gs0 + si;
        const int bb = gs >> 11;
        const int pt = idx[gs];
        const float* frow = feats + ((size_t)bb * NPTS + pt) * F_IN;
        const float* xrow = xyz   + ((size_t)bb * NPTS + pt) * 3;
        for (int c = j; c < F_IN; c += 16) sX[si][c] = frow[c];
        if (j < 3) sX[si][F_IN + j] = xrow[j];
    }
    __syncthreads();

    const int d = tid & 127;
    const int g = tid >> 7;
    float acc[8];
#pragma unroll
    for (int k = 0; k < 8; ++k) acc[k] = 0.0f;

    for (int c = 0; c < C_IN; ++c) {
        const float w = sW[c][d];
#pragma unroll
        for (int k = 0; k < 8; ++k)
            acc[k] = fmaf(sX[g * 8 + k][c], w, acc[k]);
    }

    const float bv = sB[d];
#pragma unroll
    for (int k = 0; k < 8; ++k) {
        const int gs = gs0 + g * 8 + k;
        const float v = acc[k] + bv;
        out[(size_t)gs * D_OUT + d] = fmaxf(v, 0.0f);
    }
}

// ---------------------------------------------------------------------------
extern "C" void kernel_launch(void* const* d_in, const int* in_sizes, int n_in,
                              void* d_out, int out_size, void* d_ws, size_t ws_size,
                              hipStream_t stream) {
    const float* xyz      = (const float*)d_in[0];
    const float* feats    = (const float*)d_in[1];
    const int*   init_far = (const int*)d_in[2];
    const float* W        = (const float*)d_in[3];
    const float* bias     = (const float*)d_in[4];

    float* out_newxyz = (float*)d_out;
    float* out_conv   = (float*)d_out + (size_t)B_SZ * NSAMP * 3;
    int*   idx_ws     = (int*)d_ws;

    fps_kernel<<<B_SZ, FPS_THREADS, 0, stream>>>(xyz, init_far, idx_ws, out_newxyz);

    const int nblocks = (B_SZ * NSAMP) / SAMP_PER_BLK;
    gather_linear_relu_kernel<<<nblocks, 256, 0, stream>>>(
        xyz, feats, idx_ws, W, bias, out_conv);
}